// Round 7
// baseline (120.309 us; speedup 1.0000x reference)
//
#include <hip/hip_runtime.h>
#include <hip/hip_bf16.h>
#include <math.h>

#define S_LEN 2048
#define E_DIM 1024
#define NHEAD 8
#define DHEAD 128
#define MEPS 1e-6f
#define LNEPS 1e-5f

typedef __bf16 bf16x8 __attribute__((ext_vector_type(8)));
typedef __bf16 bf16x4 __attribute__((ext_vector_type(4)));
typedef float f32x4 __attribute__((ext_vector_type(4)));
typedef float f32x16 __attribute__((ext_vector_type(16)));

__device__ inline void split8(const float* x, bf16x8& hi, bf16x8& lo) {
#pragma unroll
  for (int e = 0; e < 8; ++e) {
    float v = x[e];
    __bf16 h = (__bf16)v;
    hi[e] = h;
    lo[e] = (__bf16)(v - (float)h);
  }
}

__device__ inline int cvtpk(float a, float b) {
  int d;
  asm("v_cvt_pk_bf16_f32 %0, %1, %2" : "=v"(d) : "v"(a), "v"(b));
  return d;
}

// ---------- kernel 1: gates. wave-per-column, register weights, 16 rows/block ----------
__global__ __launch_bounds__(1024) void gates_kernel(
    const float* __restrict__ q, const float* __restrict__ k, const float* __restrict__ v,
    const float* __restrict__ igw, const float* __restrict__ igb,
    const float* __restrict__ fgw, const float* __restrict__ fgb,
    float* __restrict__ ig, double* __restrict__ ls) {
  int t = threadIdx.x, wave = t >> 6, lane = t & 63;
  int c = wave;
  const float* wrow = (c < 8) ? (igw + c * 3072) : (fgw + (c - 8) * 3072);
  float4 wreg[12];
#pragma unroll
  for (int j = 0; j < 12; ++j) wreg[j] = *(const float4*)(wrow + j * 256 + lane * 4);
  int r0 = blockIdx.x * 16;
  for (int r = 0; r < 16; ++r) {
    int row = r0 + r;
    float acc = 0.f;
#pragma unroll
    for (int j = 0; j < 12; ++j) {
      const float* xs = (j < 4) ? (q + (size_t)row * 1024 + j * 256)
                      : (j < 8) ? (k + (size_t)row * 1024 + (j - 4) * 256)
                                : (v + (size_t)row * 1024 + (j - 8) * 256);
      float4 xv = *(const float4*)(xs + lane * 4);
      acc = fmaf(xv.x, wreg[j].x, acc);
      acc = fmaf(xv.y, wreg[j].y, acc);
      acc = fmaf(xv.z, wreg[j].z, acc);
      acc = fmaf(xv.w, wreg[j].w, acc);
    }
#pragma unroll
    for (int off = 1; off < 64; off <<= 1) acc += __shfl_xor(acc, off);
    if (lane == 0) {
      if (c < 8) {
        ig[c * S_LEN + row] = acc + igb[c];
      } else {
        double x = (double)(acc + fgb[c - 8]);
        ls[(c - 8) * S_LEN + row] = fmin(x, 0.0) - log1p(exp(-fabs(x)));
      }
    }
  }
}

// ---------- kernel 2: per-head f64 scan ----------
__global__ void scan_kernel(const float* __restrict__ ig, const double* __restrict__ ls,
                            double* __restrict__ g, double* __restrict__ Mv,
                            float* __restrict__ rexpv) {
  int h = blockIdx.x;
  int lane = threadIdx.x;
  double cs0[32];
  const double* lsp = ls + h * S_LEN + lane * 32;
  double run = 0.0;
#pragma unroll
  for (int e = 0; e < 32; ++e) { run += lsp[e]; cs0[e] = run; }
  double incl = run;
#pragma unroll
  for (int off = 1; off < 64; off <<= 1) {
    double nb = __shfl_up(incl, off);
    if (lane >= off) incl += nb;
  }
  double base = __shfl_up(incl, 1);
  if (lane == 0) base = 0.0;
#pragma unroll
  for (int e = 0; e < 32; ++e) cs0[e] += base;

  const float* igp = ig + h * S_LEN + lane * 32;
  double gv[32];
#pragma unroll
  for (int e = 0; e < 32; ++e) {
    gv[e] = (double)igp[e] - cs0[e];
    g[h * S_LEN + lane * 32 + e] = gv[e];
  }
  double pm = -INFINITY;
#pragma unroll
  for (int e = 0; e < 32; ++e) { pm = fmax(pm, gv[e]); gv[e] = pm; }
  double inclm = pm;
#pragma unroll
  for (int off = 1; off < 64; off <<= 1) {
    double nb = __shfl_up(inclm, off);
    if (lane >= off) inclm = fmax(inclm, nb);
  }
  double basem = __shfl_up(inclm, 1);
  if (lane == 0) basem = -INFINITY;
#pragma unroll
  for (int e = 0; e < 32; ++e) {
    double Mi = fmax(basem, gv[e]);
    Mv[h * S_LEN + lane * 32 + e] = Mi;
    rexpv[h * S_LEN + lane * 32 + e] = __expf(-(float)(cs0[e] + Mi));
  }
}

// ---------- kernel 2c: rebase g/M to f32 per (head, 128-row q-group) ----------
__global__ __launch_bounds__(256) void rebase_kernel(
    const double* __restrict__ g, const double* __restrict__ Mv,
    float* __restrict__ gq, float* __restrict__ Mq) {
  int b = blockIdx.x;         // 128 = 8 heads x 16 groups
  int h = b >> 4, qg = b & 15;
  int tid = threadIdx.x;
  double base = Mv[h * S_LEN + qg * 128];
#pragma unroll
  for (int it = 0; it < 8; ++it) {
    int j = it * 256 + tid;
    gq[(size_t)(h * 16 + qg) * S_LEN + j] = (float)(g[h * S_LEN + j] - base);
  }
  if (tid < 128) {
    int i = qg * 128 + tid;
    Mq[h * S_LEN + i] = (float)(Mv[h * S_LEN + i] - base);
  }
}

// ---------- kernel 3: convert K,V to 32x32-MFMA fragment layouts ----------
// KfH/KfL: [h][kvt32][kch8][lane][8]   elem = K[kvt*32+(l&31)][h*128+kch*16+(l>>5)*8+e]
// VT:      [h][kvt32][f=dt*2+kch][lane][8] elem = V[kvt*32+kch*16+(l>>5)*8+e][h*128+dt*32+(l&31)]
__global__ __launch_bounds__(256) void convert_kernel(
    const float* __restrict__ k, const float* __restrict__ v,
    __bf16* __restrict__ KfH, __bf16* __restrict__ KfL, __bf16* __restrict__ VT) {
  int h = blockIdx.x >> 6, kvt = blockIdx.x & 63;
  int t = threadIdx.x;
  __shared__ float Kl[32][132], Vl[32][132];
  int kvbase = kvt * 32;
#pragma unroll
  for (int it = 0; it < 4; ++it) {
    int fid = it * 256 + t;
    int r = fid >> 5, c4 = (fid & 31) * 4;
    *(float4*)&Kl[r][c4] = *(const float4*)(k + (size_t)(kvbase + r) * E_DIM + h * DHEAD + c4);
    *(float4*)&Vl[r][c4] = *(const float4*)(v + (size_t)(kvbase + r) * E_DIM + h * DHEAD + c4);
  }
  __syncthreads();
  size_t tb = (size_t)(h * 64 + kvt) * 4096;
#pragma unroll
  for (int it = 0; it < 2; ++it) {
    int slot = it * 256 + t;
    int f = slot >> 6, l = slot & 63;
    int l31 = l & 31, hi = l >> 5;
    {
      float buf[8];
#pragma unroll
      for (int e = 0; e < 8; ++e) buf[e] = Kl[l31][f * 16 + hi * 8 + e];
      bf16x8 fh, fl; split8(buf, fh, fl);
      *(bf16x8*)(KfH + tb + (size_t)slot * 8) = fh;
      *(bf16x8*)(KfL + tb + (size_t)slot * 8) = fl;
    }
    {
      int dt = f >> 1, kch = f & 1;
      bf16x8 fh;
#pragma unroll
      for (int e = 0; e < 8; ++e) fh[e] = (__bf16)Vl[kch * 16 + hi * 8 + e][dt * 32 + l31];
      *(bf16x8*)(VT + tb + (size_t)slot * 8) = fh;
    }
  }
}

// ---------- kernel 4: attention, swapped-operand 32x32 MFMA, gload_lds pipeline ----------
__global__ __launch_bounds__(256, 2) void attn_kernel(
    const float* __restrict__ q,
    const __bf16* __restrict__ KfH, const __bf16* __restrict__ KfL,
    const __bf16* __restrict__ VT,
    const float* __restrict__ gq, const float* __restrict__ Mq,
    __bf16* __restrict__ part, float* __restrict__ bpart) {
  int idx = blockIdx.x;
  int qg = 15 - (idx >> 5);          // heavy-first
  int r = idx & 31;
  int h = r & 7;                     // head -> XCD pinned
  int quarter = r >> 3;              // 0..3 kv-quarters
  int Tq = qg + 1;                   // tiles (32 kv rows) per quarter
  int kb_lo = quarter * Tq;
  int tid = threadIdx.x, wave = tid >> 6, lane = tid & 63;
  int l31 = lane & 31, hi = lane >> 5;
  const float scale = 0.08838834764831845f;  // 1/sqrt(128)

  __shared__ char smem[49152];       // 2 bufs x [KH 8K | KL 8K | VT 8K]

  // Q^T B-fragments hi/lo: lane holds q-row (qg*128 + wave*32 + l31), d = kch*16+hi*8+e
  int qrow = qg * 128 + wave * 32 + l31;
  bf16x8 qfh[8], qfl[8];
  {
    const float* qp = q + (size_t)qrow * E_DIM + h * DHEAD + hi * 8;
#pragma unroll
    for (int kch = 0; kch < 8; ++kch) {
      float buf[8];
      *(float4*)&buf[0] = *(const float4*)(qp + kch * 16);
      *(float4*)&buf[4] = *(const float4*)(qp + kch * 16 + 4);
      split8(buf, qfh[kch], qfl[kch]);
    }
  }
  float Mreg = Mq[h * S_LEN + qrow];
  const float* gqh = gq + (size_t)(h * 16 + qg) * S_LEN;

  f32x16 acc[4];
#pragma unroll
  for (int dt = 0; dt < 4; ++dt) acc[dt] = (f32x16)(0.f);
  float bacc = 0.f;

  size_t laneoff = (size_t)lane * 8;
  auto STAGE = [&](int kb, int buf) {
    size_t tb = (size_t)(h * 64 + kb) * 4096;
    char* lb = smem + buf * 24576;
#pragma unroll
    for (int i = 0; i < 6; ++i) {
      int c = wave * 6 + i;
      const __bf16* src;
      if (c < 8)       src = KfH + tb + (size_t)c * 512 + laneoff;
      else if (c < 16) src = KfL + tb + (size_t)(c - 8) * 512 + laneoff;
      else             src = VT  + tb + (size_t)(c - 16) * 512 + laneoff;
      __builtin_amdgcn_global_load_lds(
          (const __attribute__((address_space(1))) void*)src,
          (__attribute__((address_space(3))) void*)(lb + c * 1024), 16, 0, 0);
    }
  };

  STAGE(kb_lo, 0);
  int cur = 0;
  for (int t = 0; t < Tq; ++t) {
    int kb = kb_lo + t;
    if (t + 1 < Tq) {
      STAGE(kb + 1, cur ^ 1);
      asm volatile("s_waitcnt vmcnt(6)" ::: "memory");
    } else {
      asm volatile("s_waitcnt vmcnt(0)" ::: "memory");
    }
    __builtin_amdgcn_sched_barrier(0);
    asm volatile("s_barrier" ::: "memory");

    int qrelw = qg * 128 + wave * 32 - kb * 32;   // min over lanes
    if (qrelw + 31 >= 0) {
      char* lb = smem + cur * 24576;
      int qrel = qrelw + l31;
      // ---- S^T = K . Q^T  (3-term split) ----
      f32x16 st = (f32x16)(0.f);
      __builtin_amdgcn_s_setprio(1);
#pragma unroll
      for (int kch = 0; kch < 8; ++kch) {
        bf16x8 kh = *(const bf16x8*)(lb + kch * 1024 + lane * 16);
        bf16x8 kl = *(const bf16x8*)(lb + 8192 + kch * 1024 + lane * 16);
        st = __builtin_amdgcn_mfma_f32_32x32x16_bf16(kh, qfh[kch], st, 0, 0, 0);
        st = __builtin_amdgcn_mfma_f32_32x32x16_bf16(kl, qfh[kch], st, 0, 0, 0);
        st = __builtin_amdgcn_mfma_f32_32x32x16_bf16(kh, qfl[kch], st, 0, 0, 0);
      }
      __builtin_amdgcn_s_setprio(0);
      // ---- weights ----
      float4 g4[4];
#pragma unroll
      for (int c = 0; c < 4; ++c) g4[c] = *(const float4*)(gqh + kb * 32 + 8 * c + 4 * hi);
      float p[16];
#pragma unroll
      for (int rg = 0; rg < 16; ++rg) {
        int J = (rg & 3) + 8 * (rg >> 2) + 4 * hi;
        float w = st[rg] * scale * __expf(((const float*)&g4[rg >> 2])[rg & 3] - Mreg);
        p[rg] = (J <= qrel) ? w : 0.f;
        bacc += p[rg];
      }
      // ---- pack P^T B-fragments in-register ----
#pragma unroll
      for (int kch = 0; kch < 2; ++kch) {
        const float* pp = p + kch * 8;
        int a0 = cvtpk(pp[0], pp[1]);
        int a1 = cvtpk(pp[2], pp[3]);
        int a2 = cvtpk(pp[4], pp[5]);
        int a3 = cvtpk(pp[6], pp[7]);
        asm("v_permlane32_swap_b32 %0, %1" : "+v"(a0), "+v"(a2));
        asm("v_permlane32_swap_b32 %0, %1" : "+v"(a1), "+v"(a3));
        union { int w[4]; bf16x8 v; } pb;
        pb.w[0] = a0; pb.w[1] = a1; pb.w[2] = a2; pb.w[3] = a3;
        __builtin_amdgcn_s_setprio(1);
#pragma unroll
        for (int dt = 0; dt < 4; ++dt) {
          bf16x8 va = *(const bf16x8*)(lb + 16384 + (dt * 2 + kch) * 1024 + lane * 16);
          acc[dt] = __builtin_amdgcn_mfma_f32_32x32x16_bf16(va, pb.v, acc[dt], 0, 0, 0);
        }
        __builtin_amdgcn_s_setprio(0);
      }
    }
    asm volatile("s_barrier" ::: "memory");
    cur ^= 1;
  }

  // ---- epilogue: b-combine; transpose O^T -> q-major via LDS; coalesced part writes ----
  {
    int x = __float_as_int(bacc), y = x;
    asm("v_permlane32_swap_b32 %0, %1" : "+v"(x), "+v"(y));
    float bfull = __int_as_float(x) + __int_as_float(y);
    int task = ((h * 16 + qg) * 4 + quarter);
    if (lane < 32) bpart[task * 128 + wave * 32 + lane] = bfull;

    __syncthreads();                       // staging done; LDS reusable
    char* Tls = smem + wave * 8704;        // 32 q-rows x 272B (136 bf16, 16B-aligned)
#pragma unroll
    for (int dt = 0; dt < 4; ++dt)
#pragma unroll
      for (int rgq = 0; rgq < 4; ++rgq) {
        bf16x4 pk;
        pk[0] = (__bf16)acc[dt][rgq * 4 + 0];
        pk[1] = (__bf16)acc[dt][rgq * 4 + 1];
        pk[2] = (__bf16)acc[dt][rgq * 4 + 2];
        pk[3] = (__bf16)acc[dt][rgq * 4 + 3];
        int d0 = dt * 32 + rgq * 8 + hi * 4;
        *(bf16x4*)(Tls + l31 * 272 + d0 * 2) = pk;
      }
    __syncthreads();
    __bf16* pp = part + (size_t)task * 16384;   // [128 q][128 d]
#pragma unroll
    for (int it = 0; it < 8; ++it) {
      int qr = it * 4 + (lane >> 4);
      int chunk = lane & 15;
      bf16x8 vrow = *(const bf16x8*)(Tls + qr * 272 + chunk * 16);
      *(bf16x8*)(pp + ((size_t)(wave * 32 + qr) * 128 + chunk * 8)) = vrow;
    }
  }
}

// ---------- kernel 5a: combine partials (coalesced) -> hsum f32 ----------
__global__ __launch_bounds__(256) void combine_kernel(
    const __bf16* __restrict__ part, const float* __restrict__ bpart,
    const float* __restrict__ rexpv, float* __restrict__ hsum) {
  int b = blockIdx.x;            // 128 = h*16+qg
  int h = b >> 4, qg = b & 15;
  int tid = threadIdx.x;
  int chunk = tid & 15, d0 = chunk * 8;
  int task0 = b * 4;
#pragma unroll
  for (int it = 0; it < 8; ++it) {
    int qv = it * 16 + (tid >> 4);
    float a[8] = {0.f, 0.f, 0.f, 0.f, 0.f, 0.f, 0.f, 0.f};
    float bb = 0.f;
#pragma unroll
    for (int s = 0; s < 4; ++s) {
      bf16x8 xv = *(const bf16x8*)(part + ((size_t)(task0 + s) * 128 + qv) * 128 + d0);
#pragma unroll
      for (int i = 0; i < 8; ++i) a[i] += (float)xv[i];
      bb += bpart[(task0 + s) * 128 + qv];
    }
    int tok = qg * 128 + qv;
    float norm = fmaxf(fabsf(bb), rexpv[h * S_LEN + tok]) + MEPS;
    float inv = 1.f / norm;
    float* dst = hsum + (size_t)tok * E_DIM + h * DHEAD + d0;
    float4 o0 = {a[0] * inv, a[1] * inv, a[2] * inv, a[3] * inv};
    float4 o1 = {a[4] * inv, a[5] * inv, a[6] * inv, a[7] * inv};
    *(float4*)dst = o0;
    *(float4*)(dst + 4) = o1;
  }
}

// ---------- kernel 5b: LayerNorm hsum -> out ----------
__global__ __launch_bounds__(256) void ln_kernel(const float* __restrict__ in,
                                                 const float* __restrict__ lnw,
                                                 float* __restrict__ out) {
  int s = blockIdx.x, t = threadIdx.x;
  float4 x = *(const float4*)(in + (size_t)s * E_DIM + t * 4);
  float sum = x.x + x.y + x.z + x.w;
  float sq  = x.x * x.x + x.y * x.y + x.z * x.z + x.w * x.w;
#pragma unroll
  for (int off = 1; off < 64; off <<= 1) {
    sum += __shfl_xor(sum, off);
    sq  += __shfl_xor(sq, off);
  }
  __shared__ float ps[4][2];
  int wave = t >> 6;
  if ((t & 63) == 0) { ps[wave][0] = sum; ps[wave][1] = sq; }
  __syncthreads();
  float ts = ps[0][0] + ps[1][0] + ps[2][0] + ps[3][0];
  float tq = ps[0][1] + ps[1][1] + ps[2][1] + ps[3][1];
  float mu = ts * (1.f / E_DIM);
  float var = tq * (1.f / E_DIM) - mu * mu;
  float rstd = rsqrtf(var + LNEPS);
  float4 w = *(const float4*)(lnw + t * 4);
  float4 o;
  o.x = (x.x - mu) * rstd * w.x;
  o.y = (x.y - mu) * rstd * w.y;
  o.z = (x.z - mu) * rstd * w.z;
  o.w = (x.w - mu) * rstd * w.w;
  *(float4*)(out + (size_t)s * E_DIM + t * 4) = o;
}

extern "C" void kernel_launch(void* const* d_in, const int* in_sizes, int n_in,
                              void* d_out, int out_size, void* d_ws, size_t ws_size,
                              hipStream_t stream) {
  const float* q   = (const float*)d_in[0];
  const float* k   = (const float*)d_in[1];
  const float* v   = (const float*)d_in[2];
  const float* igw = (const float*)d_in[3];
  const float* igb = (const float*)d_in[4];
  const float* fgw = (const float*)d_in[5];
  const float* fgb = (const float*)d_in[6];
  const float* lnw = (const float*)d_in[7];
  float* out = (float*)d_out;

  char* base = (char*)d_ws;
  float*  ig    = (float*)(base + 0);               // 64KB
  float*  rexpv = (float*)(base + 64 * 1024);       // 64KB
  float*  Mq    = (float*)(base + 128 * 1024);      // 64KB
  float*  bpart = (float*)(base + 192 * 1024);      // 256KB
  double* ls    = (double*)(base + 448 * 1024);     // 128KB
  double* g64   = (double*)(base + 576 * 1024);     // 128KB
  double* M64   = (double*)(base + 704 * 1024);     // 128KB
  float*  gq    = (float*)(base + 1024 * 1024);     // 1MB
  __bf16* KfH   = (__bf16*)(base + 2 * 1024 * 1024);    // 4MB
  __bf16* KfL   = (__bf16*)(base + 6 * 1024 * 1024);    // 4MB
  __bf16* VT    = (__bf16*)(base + 10 * 1024 * 1024);   // 4MB
  __bf16* part  = (__bf16*)(base + 14 * 1024 * 1024);   // 16MB
  float*  hsum  = (float*)(base + 30 * 1024 * 1024);    // 8MB

  gates_kernel<<<dim3(128), dim3(1024), 0, stream>>>(q, k, v, igw, igb, fgw, fgb, ig, ls);
  scan_kernel<<<dim3(NHEAD), dim3(64), 0, stream>>>(ig, ls, g64, M64, rexpv);
  convert_kernel<<<dim3(512), dim3(256), 0, stream>>>(k, v, KfH, KfL, VT);
  rebase_kernel<<<dim3(128), dim3(256), 0, stream>>>(g64, M64, gq, Mq);
  attn_kernel<<<dim3(512), dim3(256), 0, stream>>>(q, KfH, KfL, VT, gq, Mq, part, bpart);
  combine_kernel<<<dim3(128), dim3(256), 0, stream>>>(part, bpart, rexpv, hsum);
  ln_kernel<<<dim3(S_LEN), dim3(256), 0, stream>>>(hsum, lnw, out);
}

// Round 8
// 86.545 us; speedup vs baseline: 1.3901x; 1.3901x over previous
//
#include <hip/hip_runtime.h>
#include <hip/hip_bf16.h>
#include <math.h>

#define S_LEN 2048
#define E_DIM 1024
#define NHEAD 8
#define DHEAD 128
#define MEPS 1e-6f
#define LNEPS 1e-5f

typedef __bf16 bf16x8 __attribute__((ext_vector_type(8)));
typedef __bf16 bf16x4 __attribute__((ext_vector_type(4)));
typedef float f32x4 __attribute__((ext_vector_type(4)));
typedef float f32x16 __attribute__((ext_vector_type(16)));

__device__ inline void split8(const float* x, bf16x8& hi, bf16x8& lo) {
#pragma unroll
  for (int e = 0; e < 8; ++e) {
    float v = x[e];
    __bf16 h = (__bf16)v;
    hi[e] = h;
    lo[e] = (__bf16)(v - (float)h);
  }
}

__device__ inline int cvtpk(float a, float b) {
  int d;
  asm("v_cvt_pk_bf16_f32 %0, %1, %2" : "=v"(d) : "v"(a), "v"(b));
  return d;
}

// ---------- kernel 0: W -> B-fragment hi/lo (96 K-chunks x 64 lanes x 8) ----------
// B[k][col]: lane l holds W[c=l&15][f*32+(l>>4)*8+e]
__global__ __launch_bounds__(256) void wfrag_kernel(
    const float* __restrict__ igw, const float* __restrict__ fgw,
    __bf16* __restrict__ WfH, __bf16* __restrict__ WfL) {
  int slot = blockIdx.x * 256 + threadIdx.x;   // 6144
  int f = slot >> 6, l = slot & 63;
  int c = l & 15;
  int koff = f * 32 + (l >> 4) * 8;
  const float* wrow = (c < 8) ? (igw + c * 3072) : (fgw + (c - 8) * 3072);
  float buf[8];
#pragma unroll
  for (int e = 0; e < 8; ++e) buf[e] = wrow[koff + e];
  bf16x8 fh, fl; split8(buf, fh, fl);
  *(bf16x8*)(WfH + (size_t)slot * 8) = fh;
  *(bf16x8*)(WfL + (size_t)slot * 8) = fl;
}

// ---------- kernel 1: gates GEMM via split-bf16 MFMA ----------
// block = (row-tile of 64, K-split of 384); partials -> gpart[8][2048][16]
__global__ __launch_bounds__(256) void gates_mfma_kernel(
    const float* __restrict__ q, const float* __restrict__ k, const float* __restrict__ v,
    const __bf16* __restrict__ WfH, const __bf16* __restrict__ WfL,
    float* __restrict__ gpart) {
  int rb = blockIdx.x >> 3;        // 0..31
  int ks = blockIdx.x & 7;         // 0..7
  int r0 = rb * 64;
  int tid = threadIdx.x, wave = tid >> 6, lane = tid & 63;
  int l15 = lane & 15, hi = lane >> 4;
  __shared__ char Xl[64 * 512];    // [64 rows][128 f32], XOR-swizzled per 16B

  f32x4 cacc = (f32x4){0.f, 0.f, 0.f, 0.f};
  for (int ch = 0; ch < 3; ++ch) {
    int kb = ks * 384 + ch * 128;
    __syncthreads();
#pragma unroll
    for (int it = 0; it < 8; ++it) {
      int fid = it * 256 + tid;
      int row = fid >> 5, c4 = (fid & 31) * 4;
      int kk = kb + c4;
      const float* src = (kk < 1024) ? (q + (size_t)(r0 + row) * 1024 + kk)
                       : (kk < 2048) ? (k + (size_t)(r0 + row) * 1024 + (kk - 1024))
                                     : (v + (size_t)(r0 + row) * 1024 + (kk - 2048));
      float4 xv = *(const float4*)src;
      *(float4*)(Xl + ((row * 512 + c4 * 4) ^ ((row & 7) << 4))) = xv;
    }
    __syncthreads();
#pragma unroll
    for (int kc = 0; kc < 4; ++kc) {
      int row = wave * 16 + l15;
      int base = row * 512 + (kc * 32 + hi * 8) * 4;
      int x = (row & 7) << 4;
      float buf[8];
      *(float4*)&buf[0] = *(const float4*)(Xl + (base ^ x));
      *(float4*)&buf[4] = *(const float4*)(Xl + ((base + 16) ^ x));
      bf16x8 ah, al; split8(buf, ah, al);
      int gkc = ks * 12 + ch * 4 + kc;
      bf16x8 bh = *(const bf16x8*)(WfH + (size_t)(gkc * 64 + lane) * 8);
      bf16x8 bl = *(const bf16x8*)(WfL + (size_t)(gkc * 64 + lane) * 8);
      cacc = __builtin_amdgcn_mfma_f32_16x16x32_bf16(ah, bh, cacc, 0, 0, 0);
      cacc = __builtin_amdgcn_mfma_f32_16x16x32_bf16(ah, bl, cacc, 0, 0, 0);
      cacc = __builtin_amdgcn_mfma_f32_16x16x32_bf16(al, bh, cacc, 0, 0, 0);
    }
  }
  // C: col=l15, row=hi*4+rg
#pragma unroll
  for (int rg = 0; rg < 4; ++rg) {
    int r = r0 + wave * 16 + hi * 4 + rg;
    gpart[((size_t)ks * S_LEN + r) * 16 + l15] = cacc[rg];
  }
}

// ---------- kernel 1b: sum K-split partials + bias; ig f32, fg -> f64 logsig ----------
__global__ __launch_bounds__(256) void combine_ls_kernel(
    const float* __restrict__ gpart, const float* __restrict__ igb,
    const float* __restrict__ fgb, float* __restrict__ ig, double* __restrict__ ls) {
  int t = blockIdx.x * 256 + threadIdx.x;   // 32768
  int r = t >> 4, c = t & 15;
  float s = 0.f;
#pragma unroll
  for (int ks = 0; ks < 8; ++ks) s += gpart[((size_t)ks * S_LEN + r) * 16 + c];
  if (c < 8) {
    ig[c * S_LEN + r] = s + igb[c];
  } else {
    double x = (double)(s + fgb[c - 8]);
    ls[(c - 8) * S_LEN + r] = fmin(x, 0.0) - log1p(exp(-fabs(x)));
  }
}

// ---------- kernel 2: per-head f64 scan ----------
__global__ void scan_kernel(const float* __restrict__ ig, const double* __restrict__ ls,
                            double* __restrict__ g, double* __restrict__ Mv,
                            float* __restrict__ rexpv) {
  int h = blockIdx.x;
  int lane = threadIdx.x;
  double cs0[32];
  const double* lsp = ls + h * S_LEN + lane * 32;
  double run = 0.0;
#pragma unroll
  for (int e = 0; e < 32; ++e) { run += lsp[e]; cs0[e] = run; }
  double incl = run;
#pragma unroll
  for (int off = 1; off < 64; off <<= 1) {
    double nb = __shfl_up(incl, off);
    if (lane >= off) incl += nb;
  }
  double base = __shfl_up(incl, 1);
  if (lane == 0) base = 0.0;
#pragma unroll
  for (int e = 0; e < 32; ++e) cs0[e] += base;

  const float* igp = ig + h * S_LEN + lane * 32;
  double gv[32];
#pragma unroll
  for (int e = 0; e < 32; ++e) {
    gv[e] = (double)igp[e] - cs0[e];
    g[h * S_LEN + lane * 32 + e] = gv[e];
  }
  double pm = -INFINITY;
#pragma unroll
  for (int e = 0; e < 32; ++e) { pm = fmax(pm, gv[e]); gv[e] = pm; }
  double inclm = pm;
#pragma unroll
  for (int off = 1; off < 64; off <<= 1) {
    double nb = __shfl_up(inclm, off);
    if (lane >= off) inclm = fmax(inclm, nb);
  }
  double basem = __shfl_up(inclm, 1);
  if (lane == 0) basem = -INFINITY;
#pragma unroll
  for (int e = 0; e < 32; ++e) {
    double Mi = fmax(basem, gv[e]);
    Mv[h * S_LEN + lane * 32 + e] = Mi;
    rexpv[h * S_LEN + lane * 32 + e] = __expf(-(float)(cs0[e] + Mi));
  }
}

// ---------- kernel 2c: rebase g/M to f32 per (head, 128-row q-group) ----------
__global__ __launch_bounds__(256) void rebase_kernel(
    const double* __restrict__ g, const double* __restrict__ Mv,
    float* __restrict__ gq, float* __restrict__ Mq) {
  int b = blockIdx.x;         // 128
  int h = b >> 4, qg = b & 15;
  int tid = threadIdx.x;
  double base = Mv[h * S_LEN + qg * 128];
#pragma unroll
  for (int it = 0; it < 8; ++it) {
    int j = it * 256 + tid;
    gq[(size_t)(h * 16 + qg) * S_LEN + j] = (float)(g[h * S_LEN + j] - base);
  }
  if (tid < 128) {
    int i = qg * 128 + tid;
    Mq[h * S_LEN + i] = (float)(Mv[h * S_LEN + i] - base);
  }
}

// ---------- kernel 3: convert K,V to 32x32-MFMA fragment layouts ----------
__global__ __launch_bounds__(256) void convert_kernel(
    const float* __restrict__ k, const float* __restrict__ v,
    __bf16* __restrict__ KfH, __bf16* __restrict__ KfL, __bf16* __restrict__ VT) {
  int h = blockIdx.x >> 6, kvt = blockIdx.x & 63;
  int t = threadIdx.x;
  __shared__ float Kl[32][132], Vl[32][132];
  int kvbase = kvt * 32;
#pragma unroll
  for (int it = 0; it < 4; ++it) {
    int fid = it * 256 + t;
    int r = fid >> 5, c4 = (fid & 31) * 4;
    *(float4*)&Kl[r][c4] = *(const float4*)(k + (size_t)(kvbase + r) * E_DIM + h * DHEAD + c4);
    *(float4*)&Vl[r][c4] = *(const float4*)(v + (size_t)(kvbase + r) * E_DIM + h * DHEAD + c4);
  }
  __syncthreads();
  size_t tb = (size_t)(h * 64 + kvt) * 4096;
#pragma unroll
  for (int it = 0; it < 2; ++it) {
    int slot = it * 256 + t;
    int f = slot >> 6, l = slot & 63;
    int l31 = l & 31, hi = l >> 5;
    {
      float buf[8];
#pragma unroll
      for (int e = 0; e < 8; ++e) buf[e] = Kl[l31][f * 16 + hi * 8 + e];
      bf16x8 fh, fl; split8(buf, fh, fl);
      *(bf16x8*)(KfH + tb + (size_t)slot * 8) = fh;
      *(bf16x8*)(KfL + tb + (size_t)slot * 8) = fl;
    }
    {
      int dt = f >> 1, kch = f & 1;
      bf16x8 fh;
#pragma unroll
      for (int e = 0; e < 8; ++e) fh[e] = (__bf16)Vl[kch * 16 + hi * 8 + e][dt * 32 + l31];
      *(bf16x8*)(VT + tb + (size_t)slot * 8) = fh;
    }
  }
}

// ---------- kernel 4: attention, swapped-operand 32x32 MFMA, gload_lds pipeline ----------
__global__ __launch_bounds__(256, 2) void attn_kernel(
    const float* __restrict__ q,
    const __bf16* __restrict__ KfH, const __bf16* __restrict__ KfL,
    const __bf16* __restrict__ VT,
    const float* __restrict__ gq, const float* __restrict__ Mq,
    __bf16* __restrict__ part, float* __restrict__ bpart) {
  int idx = blockIdx.x;
  int qg = 15 - (idx >> 5);          // heavy-first
  int r = idx & 31;
  int h = r & 7;                     // head -> XCD pinned
  int quarter = r >> 3;              // 0..3 kv-quarters
  int Tq = qg + 1;
  int kb_lo = quarter * Tq;
  int tid = threadIdx.x, wave = tid >> 6, lane = tid & 63;
  int l31 = lane & 31, hi = lane >> 5;
  const float scale = 0.08838834764831845f;

  __shared__ char smem[49152];       // 2 bufs x [KH 8K | KL 8K | VT 8K]

  int qrow = qg * 128 + wave * 32 + l31;
  bf16x8 qfh[8], qfl[8];
  {
    const float* qp = q + (size_t)qrow * E_DIM + h * DHEAD + hi * 8;
#pragma unroll
    for (int kch = 0; kch < 8; ++kch) {
      float buf[8];
      *(float4*)&buf[0] = *(const float4*)(qp + kch * 16);
      *(float4*)&buf[4] = *(const float4*)(qp + kch * 16 + 4);
      split8(buf, qfh[kch], qfl[kch]);
    }
  }
  float Mreg = Mq[h * S_LEN + qrow];
  const float* gqh = gq + (size_t)(h * 16 + qg) * S_LEN;

  f32x16 acc[4];
#pragma unroll
  for (int dt = 0; dt < 4; ++dt) acc[dt] = (f32x16)(0.f);
  float bacc = 0.f;

  size_t laneoff = (size_t)lane * 8;
  auto STAGE = [&](int kb, int buf) {
    size_t tb = (size_t)(h * 64 + kb) * 4096;
    char* lb = smem + buf * 24576;
#pragma unroll
    for (int i = 0; i < 6; ++i) {
      int c = wave * 6 + i;
      const __bf16* src;
      if (c < 8)       src = KfH + tb + (size_t)c * 512 + laneoff;
      else if (c < 16) src = KfL + tb + (size_t)(c - 8) * 512 + laneoff;
      else             src = VT  + tb + (size_t)(c - 16) * 512 + laneoff;
      __builtin_amdgcn_global_load_lds(
          (const __attribute__((address_space(1))) void*)src,
          (__attribute__((address_space(3))) void*)(lb + c * 1024), 16, 0, 0);
    }
  };

  STAGE(kb_lo, 0);
  int cur = 0;
  for (int t = 0; t < Tq; ++t) {
    int kb = kb_lo + t;
    if (t + 1 < Tq) {
      STAGE(kb + 1, cur ^ 1);
      asm volatile("s_waitcnt vmcnt(6)" ::: "memory");
    } else {
      asm volatile("s_waitcnt vmcnt(0)" ::: "memory");
    }
    __builtin_amdgcn_sched_barrier(0);
    asm volatile("s_barrier" ::: "memory");

    int qrelw = qg * 128 + wave * 32 - kb * 32;
    if (qrelw + 31 >= 0) {
      char* lb = smem + cur * 24576;
      int qrel = qrelw + l31;
      f32x16 st = (f32x16)(0.f);
      __builtin_amdgcn_s_setprio(1);
#pragma unroll
      for (int kch = 0; kch < 8; ++kch) {
        bf16x8 kh = *(const bf16x8*)(lb + kch * 1024 + lane * 16);
        bf16x8 kl = *(const bf16x8*)(lb + 8192 + kch * 1024 + lane * 16);
        st = __builtin_amdgcn_mfma_f32_32x32x16_bf16(kh, qfh[kch], st, 0, 0, 0);
        st = __builtin_amdgcn_mfma_f32_32x32x16_bf16(kl, qfh[kch], st, 0, 0, 0);
        st = __builtin_amdgcn_mfma_f32_32x32x16_bf16(kh, qfl[kch], st, 0, 0, 0);
      }
      __builtin_amdgcn_s_setprio(0);
      float4 g4[4];
#pragma unroll
      for (int c = 0; c < 4; ++c) g4[c] = *(const float4*)(gqh + kb * 32 + 8 * c + 4 * hi);
      float p[16];
#pragma unroll
      for (int rg = 0; rg < 16; ++rg) {
        int J = (rg & 3) + 8 * (rg >> 2) + 4 * hi;
        float w = st[rg] * scale * __expf(((const float*)&g4[rg >> 2])[rg & 3] - Mreg);
        p[rg] = (J <= qrel) ? w : 0.f;
        bacc += p[rg];
      }
#pragma unroll
      for (int kch = 0; kch < 2; ++kch) {
        const float* pp = p + kch * 8;
        int a0 = cvtpk(pp[0], pp[1]);
        int a1 = cvtpk(pp[2], pp[3]);
        int a2 = cvtpk(pp[4], pp[5]);
        int a3 = cvtpk(pp[6], pp[7]);
        asm("v_permlane32_swap_b32 %0, %1" : "+v"(a0), "+v"(a2));
        asm("v_permlane32_swap_b32 %0, %1" : "+v"(a1), "+v"(a3));
        union { int w[4]; bf16x8 v; } pb;
        pb.w[0] = a0; pb.w[1] = a1; pb.w[2] = a2; pb.w[3] = a3;
        __builtin_amdgcn_s_setprio(1);
#pragma unroll
        for (int dt = 0; dt < 4; ++dt) {
          bf16x8 va = *(const bf16x8*)(lb + 16384 + (dt * 2 + kch) * 1024 + lane * 16);
          acc[dt] = __builtin_amdgcn_mfma_f32_32x32x16_bf16(va, pb.v, acc[dt], 0, 0, 0);
        }
        __builtin_amdgcn_s_setprio(0);
      }
    }
    asm volatile("s_barrier" ::: "memory");
    cur ^= 1;
  }

  // epilogue: b-combine; transpose O^T -> q-major via LDS; coalesced part writes
  {
    int x = __float_as_int(bacc), y = x;
    asm("v_permlane32_swap_b32 %0, %1" : "+v"(x), "+v"(y));
    float bfull = __int_as_float(x) + __int_as_float(y);
    int task = ((h * 16 + qg) * 4 + quarter);
    if (lane < 32) bpart[task * 128 + wave * 32 + lane] = bfull;

    __syncthreads();
    char* Tls = smem + wave * 8704;        // 32 q x 272B
#pragma unroll
    for (int dt = 0; dt < 4; ++dt)
#pragma unroll
      for (int rgq = 0; rgq < 4; ++rgq) {
        bf16x4 pk;
        pk[0] = (__bf16)acc[dt][rgq * 4 + 0];
        pk[1] = (__bf16)acc[dt][rgq * 4 + 1];
        pk[2] = (__bf16)acc[dt][rgq * 4 + 2];
        pk[3] = (__bf16)acc[dt][rgq * 4 + 3];
        int d0 = dt * 32 + rgq * 8 + hi * 4;
        *(bf16x4*)(Tls + l31 * 272 + d0 * 2) = pk;
      }
    __syncthreads();
    __bf16* pp = part + (size_t)task * 16384;   // [128 q][128 d]
#pragma unroll
    for (int it = 0; it < 8; ++it) {
      int qr = it * 4 + (lane >> 4);
      int chunk = lane & 15;
      bf16x8 vrow = *(const bf16x8*)(Tls + qr * 272 + chunk * 16);
      *(bf16x8*)(pp + ((size_t)(wave * 32 + qr) * 128 + chunk * 8)) = vrow;
    }
  }
}

// ---------- kernel 5a: combine partials (coalesced) -> hsum f32 ----------
__global__ __launch_bounds__(256) void combine_kernel(
    const __bf16* __restrict__ part, const float* __restrict__ bpart,
    const float* __restrict__ rexpv, float* __restrict__ hsum) {
  int b = blockIdx.x;            // 128 = h*16+qg
  int h = b >> 4, qg = b & 15;
  int tid = threadIdx.x;
  int chunk = tid & 15, d0 = chunk * 8;
  int task0 = b * 4;
#pragma unroll
  for (int it = 0; it < 8; ++it) {
    int qv = it * 16 + (tid >> 4);
    float a[8] = {0.f, 0.f, 0.f, 0.f, 0.f, 0.f, 0.f, 0.f};
    float bb = 0.f;
#pragma unroll
    for (int s = 0; s < 4; ++s) {
      bf16x8 xv = *(const bf16x8*)(part + ((size_t)(task0 + s) * 128 + qv) * 128 + d0);
#pragma unroll
      for (int i = 0; i < 8; ++i) a[i] += (float)xv[i];
      bb += bpart[(task0 + s) * 128 + qv];
    }
    int tok = qg * 128 + qv;
    float norm = fmaxf(fabsf(bb), rexpv[h * S_LEN + tok]) + MEPS;
    float inv = 1.f / norm;
    float* dst = hsum + (size_t)tok * E_DIM + h * DHEAD + d0;
    float4 o0 = {a[0] * inv, a[1] * inv, a[2] * inv, a[3] * inv};
    float4 o1 = {a[4] * inv, a[5] * inv, a[6] * inv, a[7] * inv};
    *(float4*)dst = o0;
    *(float4*)(dst + 4) = o1;
  }
}

// ---------- kernel 5b: LayerNorm hsum -> out ----------
__global__ __launch_bounds__(256) void ln_kernel(const float* __restrict__ in,
                                                 const float* __restrict__ lnw,
                                                 float* __restrict__ out) {
  int s = blockIdx.x, t = threadIdx.x;
  float4 x = *(const float4*)(in + (size_t)s * E_DIM + t * 4);
  float sum = x.x + x.y + x.z + x.w;
  float sq  = x.x * x.x + x.y * x.y + x.z * x.z + x.w * x.w;
#pragma unroll
  for (int off = 1; off < 64; off <<= 1) {
    sum += __shfl_xor(sum, off);
    sq  += __shfl_xor(sq, off);
  }
  __shared__ float ps[4][2];
  int wave = t >> 6;
  if ((t & 63) == 0) { ps[wave][0] = sum; ps[wave][1] = sq; }
  __syncthreads();
  float ts = ps[0][0] + ps[1][0] + ps[2][0] + ps[3][0];
  float tq = ps[0][1] + ps[1][1] + ps[2][1] + ps[3][1];
  float mu = ts * (1.f / E_DIM);
  float var = tq * (1.f / E_DIM) - mu * mu;
  float rstd = rsqrtf(var + LNEPS);
  float4 w = *(const float4*)(lnw + t * 4);
  float4 o;
  o.x = (x.x - mu) * rstd * w.x;
  o.y = (x.y - mu) * rstd * w.y;
  o.z = (x.z - mu) * rstd * w.z;
  o.w = (x.w - mu) * rstd * w.w;
  *(float4*)(out + (size_t)s * E_DIM + t * 4) = o;
}

extern "C" void kernel_launch(void* const* d_in, const int* in_sizes, int n_in,
                              void* d_out, int out_size, void* d_ws, size_t ws_size,
                              hipStream_t stream) {
  const float* q   = (const float*)d_in[0];
  const float* k   = (const float*)d_in[1];
  const float* v   = (const float*)d_in[2];
  const float* igw = (const float*)d_in[3];
  const float* igb = (const float*)d_in[4];
  const float* fgw = (const float*)d_in[5];
  const float* fgb = (const float*)d_in[6];
  const float* lnw = (const float*)d_in[7];
  float* out = (float*)d_out;

  char* base = (char*)d_ws;
  float*  ig    = (float*)(base + 0);               // 64KB
  float*  rexpv = (float*)(base + 64 * 1024);       // 64KB
  float*  Mq    = (float*)(base + 128 * 1024);      // 64KB
  float*  bpart = (float*)(base + 192 * 1024);      // 256KB
  double* ls    = (double*)(base + 448 * 1024);     // 128KB
  double* g64   = (double*)(base + 576 * 1024);     // 128KB
  double* M64   = (double*)(base + 704 * 1024);     // 128KB
  __bf16* WfH   = (__bf16*)(base + 832 * 1024);     // 96KB
  __bf16* WfL   = (__bf16*)(base + 928 * 1024);     // 96KB
  float*  gq    = (float*)(base + 1024 * 1024);     // 1MB
  __bf16* KfH   = (__bf16*)(base + 2 * 1024 * 1024);    // 4MB
  __bf16* KfL   = (__bf16*)(base + 6 * 1024 * 1024);    // 4MB
  __bf16* VT    = (__bf16*)(base + 10 * 1024 * 1024);   // 4MB
  __bf16* part  = (__bf16*)(base + 14 * 1024 * 1024);   // 16MB
  float*  hsum  = (float*)(base + 30 * 1024 * 1024);    // 8MB (late-lived)
  float*  gpart = (float*)(base + 30 * 1024 * 1024);    // 1MB (early-lived, aliases hsum)

  wfrag_kernel<<<dim3(24), dim3(256), 0, stream>>>(igw, fgw, WfH, WfL);
  gates_mfma_kernel<<<dim3(256), dim3(256), 0, stream>>>(q, k, v, WfH, WfL, gpart);
  combine_ls_kernel<<<dim3(128), dim3(256), 0, stream>>>(gpart, igb, fgb, ig, ls);
  scan_kernel<<<dim3(NHEAD), dim3(64), 0, stream>>>(ig, ls, g64, M64, rexpv);
  convert_kernel<<<dim3(512), dim3(256), 0, stream>>>(k, v, KfH, KfL, VT);
  rebase_kernel<<<dim3(128), dim3(256), 0, stream>>>(g64, M64, gq, Mq);
  attn_kernel<<<dim3(512), dim3(256), 0, stream>>>(q, KfH, KfL, VT, gq, Mq, part, bpart);
  combine_kernel<<<dim3(128), dim3(256), 0, stream>>>(part, bpart, rexpv, hsum);
  ln_kernel<<<dim3(S_LEN), dim3(256), 0, stream>>>(hsum, lnw, out);
}